// Round 4
// baseline (15.137 us; speedup 1.0000x reference)
//
#include <hip/hip_runtime.h>
#include <math.h>

#define TPB 256
#define TOK 4
#define TILE (TPB * TOK)        // 1024 tokens per block
#define HALO 14                 // MAX_SPAN_WIDTH - 1
#define WIN (TOK + 2 * HALO)    // 32-value per-thread window
#define NEGINF (-10000.0f)
#define SENT (-1.0e30f)         // out-of-row sentinel (invalid spans lose every max)
#define LDSF 1056               // TILE+2*HALO=1052, padded to 32-float multiple for swizzle

// Bank-conflict swizzle: XOR bank-quad bits (f>>2)&7 with block bits (f>>5)&7.
// Uniform within any aligned float4 (and any 8B-aligned float2), so vector
// LDS ops stay contiguous & aligned. Lanes at 64B stride land on distinct
// bank-quads -> conflict-free ds_read_b128 / ds_write_b64.
__device__ __forceinline__ int swz(int f) { return f ^ (((f >> 5) & 7) << 2); }

// A[] holds (in place) the sparse-table level K = 2^floor(log2 W) when called.
// Span mins Q[u] for span start s = 15-W+u; token j needs max over Q[j..j+W-1].
// All indices compile-time -> registers only.
template <int W>
__device__ __forceinline__ void do_width(const float (&A)[WIN], float wt,
                                         float &b0, float &b1, float &b2,
                                         float &b3) {
  constexpr int K = (W < 4) ? 2 : ((W < 8) ? 4 : 8);
  float Q[W + 3];
#pragma unroll
  for (int u = 0; u < W + 3; ++u) {
    const int s = (HALO + 1) - W + u;  // 15 - W + u
    if constexpr (W == K)
      Q[u] = A[s];
    else
      Q[u] = fminf(A[s], A[s + (W - K)]);
  }
  float m0, m1, m2, m3;
  if constexpr (W == 2) {
    m0 = fmaxf(Q[0], Q[1]);
    m1 = fmaxf(Q[1], Q[2]);
    m2 = fmaxf(Q[2], Q[3]);
    m3 = fmaxf(Q[3], Q[4]);
  } else if constexpr (W == 3) {
    m0 = fmaxf(Q[0], fmaxf(Q[1], Q[2]));
    m1 = fmaxf(Q[1], fmaxf(Q[2], Q[3]));
    m2 = fmaxf(Q[2], fmaxf(Q[3], Q[4]));
    m3 = fmaxf(Q[3], fmaxf(Q[4], Q[5]));
  } else {
    float core = Q[3];  // max Q[3..W-1]; empty tail loop for W==4
#pragma unroll
    for (int u = 4; u < W; ++u) core = fmaxf(core, Q[u]);
    const float q2c = fmaxf(Q[2], core);
    const float dW = fmaxf(Q[W], Q[W + 1]);
    m0 = fmaxf(fmaxf(Q[0], Q[1]), q2c);     // u in [0, W-1]
    m1 = fmaxf(fmaxf(Q[1], Q[W]), q2c);     // u in [1, W]
    m2 = fmaxf(q2c, dW);                    // u in [2, W+1]
    m3 = fmaxf(fmaxf(core, Q[W + 2]), dW);  // u in [3, W+2]
  }
  b0 = fmaxf(b0, m0 * wt);
  b1 = fmaxf(b1, m1 * wt);
  b2 = fmaxf(b2, m2 * wt);
  b3 = fmaxf(b3, m3 * wt);
}

// weight for width W, broadcast from the lane that computed it (SGPR-uniform)
#define WT(W) __int_as_float(__builtin_amdgcn_readlane(wbits, (W) - 2))

__global__ __launch_bounds__(TPB, 4) void span_kernel(
    const float *__restrict__ ts, const int *__restrict__ mask,
    const float *__restrict__ wlog, const float *__restrict__ gamma_p,
    float *__restrict__ out, int N, int tiles_per_row) {
  __shared__ __align__(16) float sm[LDSF];
  const int tid = threadIdx.x;
  const int row = blockIdx.x / tiles_per_row;
  const int t0 = (blockIdx.x % tiles_per_row) * TILE;
  const float *tsrow = ts + (size_t)row * N;
  const int *mrow = mask + (size_t)row * N;

  // ---- staging: one int4 + one float4 per thread for the main tile ----
  const int j = tid * TOK;  // 0..1020
  const int g = t0 + j;
  const int4 mv = *reinterpret_cast<const int4 *>(&mrow[g]);
  const float4 tv = *reinterpret_cast<const float4 *>(&tsrow[g]);
  {
    float2 w01, w23;
    w01.x = mv.x ? tv.x : NEGINF;
    w01.y = mv.y ? tv.y : NEGINF;
    w23.x = mv.z ? tv.z : NEGINF;
    w23.y = mv.w ? tv.w : NEGINF;
    const int f0 = HALO + j;  // %4 == 2 -> both float2s quad-uniform
    *reinterpret_cast<float2 *>(&sm[swz(f0)]) = w01;
    *reinterpret_cast<float2 *>(&sm[swz(f0 + 2)]) = w23;
  }
  // halo: lanes 0..27 fill left(14)+right(14) edges (out-of-row -> sentinel)
  if (tid < 2 * HALO) {
    const int hk = (tid < HALO) ? tid : (TILE + tid);  // sm index
    const int tok = t0 - HALO + hk;                    // global token
    float v = SENT;
    if (tok >= 0 && tok < N) v = mrow[tok] ? tsrow[tok] : NEGINF;
    sm[swz(hk)] = v;
  }

  // ---- softmax of the 15 width logits: wave-parallel in 16-lane groups ----
  unsigned wbits;
  {
    const int li = tid & 15;
    float v = (li < 15) ? wlog[li] : -3.4e38f;
    float mx = v;
#pragma unroll
    for (int m = 1; m < 16; m <<= 1) mx = fmaxf(mx, __shfl_xor(mx, m, 64));
    const float e = expf(v - mx);  // li==15: exp(-inf) = 0
    float s = e;
#pragma unroll
    for (int m = 1; m < 16; m <<= 1) s += __shfl_xor(s, m, 64);
    wbits = __float_as_uint(e / s);
  }
  const float gamma = *gamma_p;

  __syncthreads();

  // ---- per-thread 32-value window (8x conflict-free ds_read_b128) ----
  float A[WIN];
#pragma unroll
  for (int q = 0; q < WIN / 4; ++q) {
    const float4 v = *reinterpret_cast<const float4 *>(&sm[swz(j + 4 * q)]);
    A[4 * q + 0] = v.x;
    A[4 * q + 1] = v.y;
    A[4 * q + 2] = v.z;
    A[4 * q + 3] = v.w;
  }
  // width-1 boost: the masked scores themselves (before A is overwritten)
  float b0 = A[HALO + 0], b1 = A[HALO + 1], b2 = A[HALO + 2], b3 = A[HALO + 3];

  // ---- in-place sparse table: ascending update never reads a clobbered slot
#pragma unroll
  for (int x = 0; x < WIN - 1; ++x) A[x] = fminf(A[x], A[x + 1]);  // P2
  do_width<2>(A, WT(2), b0, b1, b2, b3);
  do_width<3>(A, WT(3), b0, b1, b2, b3);

#pragma unroll
  for (int x = 0; x < WIN - 3; ++x) A[x] = fminf(A[x], A[x + 2]);  // P4
  do_width<4>(A, WT(4), b0, b1, b2, b3);
  do_width<5>(A, WT(5), b0, b1, b2, b3);
  do_width<6>(A, WT(6), b0, b1, b2, b3);
  do_width<7>(A, WT(7), b0, b1, b2, b3);

#pragma unroll
  for (int x = 0; x < WIN - 7; ++x) A[x] = fminf(A[x], A[x + 4]);  // P8
  do_width<8>(A, WT(8), b0, b1, b2, b3);
  do_width<9>(A, WT(9), b0, b1, b2, b3);
  do_width<10>(A, WT(10), b0, b1, b2, b3);
  do_width<11>(A, WT(11), b0, b1, b2, b3);
  do_width<12>(A, WT(12), b0, b1, b2, b3);
  do_width<13>(A, WT(13), b0, b1, b2, b3);
  do_width<14>(A, WT(14), b0, b1, b2, b3);
  do_width<15>(A, WT(15), b0, b1, b2, b3);

  // ---- output: raw scores kept in registers from staging ----
  float4 o;
  o.x = tv.x + gamma * b0;
  o.y = tv.y + gamma * b1;
  o.z = tv.z + gamma * b2;
  o.w = tv.w + gamma * b3;
  *reinterpret_cast<float4 *>(&out[(size_t)row * N + g]) = o;
}

extern "C" void kernel_launch(void *const *d_in, const int *in_sizes, int n_in,
                              void *d_out, int out_size, void *d_ws,
                              size_t ws_size, hipStream_t stream) {
  const float *ts = (const float *)d_in[0];
  const int *mask = (const int *)d_in[1];
  const float *wlog = (const float *)d_in[2];
  const float *gamma_p = (const float *)d_in[3];
  float *out = (float *)d_out;
  const int N = 8192;          // fixed problem shape (B=256, N=8192)
  const int B = in_sizes[0] / N;
  const int tiles = N / TILE;  // 8
  span_kernel<<<dim3(B * tiles), dim3(TPB), 0, stream>>>(ts, mask, wlog,
                                                         gamma_p, out, N,
                                                         tiles);
}

// Round 5
// 13.450 us; speedup vs baseline: 1.1254x; 1.1254x over previous
//
#include <hip/hip_runtime.h>
#include <math.h>

#define TPB 256
#define TOK 8
#define TILE (TPB * TOK)        // 2048 tokens per block
#define HALO 14                 // MAX_SPAN_WIDTH - 1
#define WIN (TOK + 2 * HALO)    // 36-value per-thread window
#define NEGINF (-10000.0f)
#define SENT (-1.0e30f)         // out-of-row sentinel (invalid spans lose every max)
#define LDSF 2080               // TILE+2*HALO=2076, padded

// Bank-conflict swizzle: XOR bank-quad bits (f>>2)&7 with bits (f>>5)&7.
// Uniform within any aligned quad -> aligned float2/float4 ops stay
// contiguous & aligned. Essential at TOK=8: lane stride is 32 floats,
// which unswizzled puts all lanes on the same 4 banks.
__device__ __forceinline__ int swz(int f) { return f ^ (((f >> 5) & 7) << 2); }

// A[] holds (in place) sparse-table level K = 2^floor(log2 W) when called.
// Q[u] = min of the width-W span starting at window pos 15-W+u, u=0..W+6;
// token k (window pos 14+k, k=0..7) needs max over Q[k..k+W-1].
// Widths >=8: all 8 intervals contain anchor 7 -> shared prefix/suffix.
// Widths 4..7: two 4-token groups anchored at 3 and 7. All indices static.
template <int W>
__device__ __forceinline__ void do_width(const float (&A)[WIN], float wt,
                                         float (&b)[TOK]) {
  constexpr int K = (W < 4) ? 2 : ((W < 8) ? 4 : 8);
  constexpr int S0 = (HALO + 1) - W;  // 15 - W
  constexpr int NQ = W + TOK - 1;     // W + 7
  float Q[NQ];
#pragma unroll
  for (int u = 0; u < NQ; ++u) {
    if constexpr (W == K)
      Q[u] = A[S0 + u];
    else
      Q[u] = fminf(A[S0 + u], A[S0 + u + (W - K)]);
  }
  float m[TOK];
  if constexpr (W == 2) {
#pragma unroll
    for (int k = 0; k < TOK; ++k) m[k] = fmaxf(Q[k], Q[k + 1]);
  } else if constexpr (W == 3) {
#pragma unroll
    for (int k = 0; k < TOK; ++k)
      m[k] = fmaxf(fmaxf(Q[k], Q[k + 1]), Q[k + 2]);  // v_max3
  } else if constexpr (W < 8) {
    // tokens 0..3 anchored at Q[3], tokens 4..7 anchored at Q[7]
    float SA[4];
    SA[3] = Q[3];
#pragma unroll
    for (int k = 2; k >= 0; --k) SA[k] = fmaxf(Q[k], SA[k + 1]);
    float TA[W];
    TA[0] = Q[3];
#pragma unroll
    for (int j = 1; j < W; ++j) TA[j] = fmaxf(TA[j - 1], Q[3 + j]);
#pragma unroll
    for (int k = 0; k < 4; ++k) m[k] = fmaxf(SA[k], TA[k + W - 4]);
    float SB[4];
    SB[3] = Q[7];
#pragma unroll
    for (int k = 2; k >= 0; --k) SB[k] = fmaxf(Q[4 + k], SB[k + 1]);
    float TB[W];
    TB[0] = Q[7];
#pragma unroll
    for (int j = 1; j < W; ++j) TB[j] = fmaxf(TB[j - 1], Q[7 + j]);
#pragma unroll
    for (int k = 0; k < 4; ++k) m[4 + k] = fmaxf(SB[k], TB[k + W - 4]);
  } else {
    float S[8];
    S[7] = Q[7];
#pragma unroll
    for (int k = 6; k >= 0; --k) S[k] = fmaxf(Q[k], S[k + 1]);
    float T[W];
    T[0] = Q[7];
#pragma unroll
    for (int j = 1; j < W; ++j) T[j] = fmaxf(T[j - 1], Q[7 + j]);
#pragma unroll
    for (int k = 0; k < TOK; ++k) m[k] = fmaxf(S[k], T[k + W - 8]);
  }
#pragma unroll
  for (int k = 0; k < TOK; ++k) b[k] = fmaxf(b[k], m[k] * wt);
}

__global__ __launch_bounds__(TPB, 4) void span_kernel(
    const float *__restrict__ ts, const int *__restrict__ mask,
    const float *__restrict__ wlog, const float *__restrict__ gamma_p,
    float *__restrict__ out, int N, int tiles_per_row) {
  __shared__ __align__(16) float sm[LDSF];
  __shared__ float swt[15];  // 14 softmax weights + gamma at [14]
  const int tid = threadIdx.x;
  const int row = blockIdx.x / tiles_per_row;
  const int t0 = (blockIdx.x % tiles_per_row) * TILE;
  const float *tsrow = ts + (size_t)row * N;
  const int *mrow = mask + (size_t)row * N;

  // ---- staging: 8 tokens/thread (2x int4 + 2x float4) ----
  const int j = tid * TOK;  // 0..2040
  const int g = t0 + j;
  const int4 mv0 = *reinterpret_cast<const int4 *>(&mrow[g]);
  const int4 mv1 = *reinterpret_cast<const int4 *>(&mrow[g + 4]);
  const float4 tv0 = *reinterpret_cast<const float4 *>(&tsrow[g]);
  const float4 tv1 = *reinterpret_cast<const float4 *>(&tsrow[g + 4]);
  {
    const int f0 = HALO + j;  // %8 == 6
    float2 a;                 // f0 .. f0+1 (quad pos 2,3)
    a.x = mv0.x ? tv0.x : NEGINF;
    a.y = mv0.y ? tv0.y : NEGINF;
    float4 c;                 // f0+2 .. f0+5 (quad-aligned)
    c.x = mv0.z ? tv0.z : NEGINF;
    c.y = mv0.w ? tv0.w : NEGINF;
    c.z = mv1.x ? tv1.x : NEGINF;
    c.w = mv1.y ? tv1.y : NEGINF;
    float2 d;                 // f0+6 .. f0+7 (quad pos 0,1)
    d.x = mv1.z ? tv1.z : NEGINF;
    d.y = mv1.w ? tv1.w : NEGINF;
    *reinterpret_cast<float2 *>(&sm[swz(f0)]) = a;
    *reinterpret_cast<float4 *>(&sm[swz(f0 + 2)]) = c;
    *reinterpret_cast<float2 *>(&sm[swz(f0 + 6)]) = d;
  }
  // halo: lanes 0..27 fill left(14)+right(14) edges (out-of-row -> sentinel)
  if (tid < 2 * HALO) {
    const int hk = (tid < HALO) ? tid : (TILE + tid);  // logical sm index
    const int tok = t0 - HALO + hk;                    // global token
    float v = SENT;
    if (tok >= 0 && tok < N) v = mrow[tok] ? tsrow[tok] : NEGINF;
    sm[swz(hk)] = v;
  }
  // softmax of width logits: ONE thread (serial order bit-matches np ref)
  if (tid == TPB - 1) {
    float e[15], mx = -3.4e38f;
#pragma unroll
    for (int i = 0; i < 15; ++i) {
      e[i] = wlog[i];
      mx = fmaxf(mx, e[i]);
    }
    float ssum = 0.0f;
#pragma unroll
    for (int i = 0; i < 15; ++i) {
      e[i] = expf(e[i] - mx);
      ssum += e[i];
    }
    const float inv = 1.0f / ssum;
#pragma unroll
    for (int i = 0; i < 14; ++i) swt[i] = e[i] * inv;
    swt[14] = *gamma_p;
  }
  __syncthreads();

  // ---- per-thread 36-value window (9x conflict-free ds_read_b128) ----
  float A[WIN];
#pragma unroll
  for (int q = 0; q < WIN / 4; ++q) {
    const float4 v = *reinterpret_cast<const float4 *>(&sm[swz(j + 4 * q)]);
    A[4 * q + 0] = v.x;
    A[4 * q + 1] = v.y;
    A[4 * q + 2] = v.z;
    A[4 * q + 3] = v.w;
  }
  // width-1 boost: the masked scores themselves (before A is overwritten)
  float b[TOK];
#pragma unroll
  for (int k = 0; k < TOK; ++k) b[k] = A[HALO + k];

  // ---- in-place sparse table: ascending update never reads a clobbered slot
#pragma unroll
  for (int x = 0; x < WIN - 1; ++x) A[x] = fminf(A[x], A[x + 1]);  // P2
  do_width<2>(A, swt[0], b);
  do_width<3>(A, swt[1], b);

#pragma unroll
  for (int x = 0; x < WIN - 3; ++x) A[x] = fminf(A[x], A[x + 2]);  // P4
  do_width<4>(A, swt[2], b);
  do_width<5>(A, swt[3], b);
  do_width<6>(A, swt[4], b);
  do_width<7>(A, swt[5], b);

#pragma unroll
  for (int x = 0; x < WIN - 7; ++x) A[x] = fminf(A[x], A[x + 4]);  // P8
  do_width<8>(A, swt[6], b);
  do_width<9>(A, swt[7], b);
  do_width<10>(A, swt[8], b);
  do_width<11>(A, swt[9], b);
  do_width<12>(A, swt[10], b);
  do_width<13>(A, swt[11], b);
  do_width<14>(A, swt[12], b);
  do_width<15>(A, swt[13], b);

  // ---- output: raw scores kept in registers from staging ----
  const float gamma = swt[14];
  float4 o0, o1;
  o0.x = tv0.x + gamma * b[0];
  o0.y = tv0.y + gamma * b[1];
  o0.z = tv0.z + gamma * b[2];
  o0.w = tv0.w + gamma * b[3];
  o1.x = tv1.x + gamma * b[4];
  o1.y = tv1.y + gamma * b[5];
  o1.z = tv1.z + gamma * b[6];
  o1.w = tv1.w + gamma * b[7];
  float *orow = out + (size_t)row * N + g;
  *reinterpret_cast<float4 *>(orow) = o0;
  *reinterpret_cast<float4 *>(orow + 4) = o1;
}

extern "C" void kernel_launch(void *const *d_in, const int *in_sizes, int n_in,
                              void *d_out, int out_size, void *d_ws,
                              size_t ws_size, hipStream_t stream) {
  const float *ts = (const float *)d_in[0];
  const int *mask = (const int *)d_in[1];
  const float *wlog = (const float *)d_in[2];
  const float *gamma_p = (const float *)d_in[3];
  float *out = (float *)d_out;
  const int N = 8192;          // fixed problem shape (B=256, N=8192)
  const int B = in_sizes[0] / N;
  const int tiles = N / TILE;  // 4
  span_kernel<<<dim3(B * tiles), dim3(TPB), 0, stream>>>(ts, mask, wlog,
                                                         gamma_p, out, N,
                                                         tiles);
}